// Round 19
// baseline (117.062 us; speedup 1.0000x reference)
//
#include <hip/hip_runtime.h>
#include <hip/hip_bf16.h>
#include <cstddef>
#include <cstdint>

typedef __attribute__((ext_vector_type(8))) short s16x8;   // bf16 A/B frag
typedef __attribute__((ext_vector_type(4))) short s16x4;
typedef __attribute__((ext_vector_type(4))) float f32x4;   // MFMA acc

namespace {
constexpr int NB   = 128;
constexpr int NCH  = 256;
constexpr int SPA  = 1024;
constexpr int NCC  = 64;
constexpr int MT   = NB * SPA;     // 131072
constexpr float EPSV = 1e-5f;
}

__device__ inline unsigned short f2bf(float f) {
    union { float f; unsigned u; } v; v.f = f;
    unsigned r = v.u + 0x7fffu + ((v.u >> 16) & 1u);   // RNE
    return (unsigned short)(r >> 16);
}

__device__ inline s16x8 cvt8(float4 a, float4 b) {
    union { __hip_bfloat162 h[4]; s16x8 s; } u;
    u.h[0] = __float22bfloat162_rn(make_float2(a.x, a.y));
    u.h[1] = __float22bfloat162_rn(make_float2(a.z, a.w));
    u.h[2] = __float22bfloat162_rn(make_float2(b.x, b.y));
    u.h[3] = __float22bfloat162_rn(make_float2(b.z, b.w));
    return u.s;
}

__device__ inline s16x8 pack8(const float* v) {
    union { __hip_bfloat162 h[4]; s16x8 s; } u;
    u.h[0] = __float22bfloat162_rn(make_float2(v[0], v[1]));
    u.h[1] = __float22bfloat162_rn(make_float2(v[2], v[3]));
    u.h[2] = __float22bfloat162_rn(make_float2(v[4], v[5]));
    u.h[3] = __float22bfloat162_rn(make_float2(v[6], v[7]));
    return u.s;
}

// ---------------------------------------------------------------------------
// Kernel 1 (round-17 proven, verbatim): partial Gram via bf16 MFMA,
// gload_lds staging + 16B-unit XOR swizzle (linear LDS dest, pre-swizzled
// global source, swizzled read -> conflict-free 8-phase ds_read_b128),
// double-buffered Xt. Grid 512 (g*128+b), 256 thr = 4 waves.
// ---------------------------------------------------------------------------
__global__ __launch_bounds__(256) void zca_stats(const float* __restrict__ X,
                                                 float* __restrict__ Gpart,
                                                 float* __restrict__ Spart) {
    const int bid = blockIdx.x;
    const int g = bid >> 7, b = bid & 127;
    const int t = threadIdx.x;
    const int w = t >> 6, l = t & 63;
    const int lr = l & 15, gq = l >> 4;
    const int h    = w >> 1;   // m-half of tile (0: cols 0-31, 1: 32-63)
    const int half = w & 1;    // MFMA tile subset (0: first 5, 1: last 5)

    __shared__ float smem[2 * 64 * 64];           // Xt[2][64][64] (32 KB)
    float (*Xt)[64][64] = (float (*)[64][64])smem;

    const float* xb = X + ((size_t)b * NCH + (size_t)g * NCC) * SPA;
    const int lh = l >> 4;

    // stage: LDS dest linear (lane*16B); global source col pre-swizzled so
    // LDS unit u of row r holds global unit u ^ sw(r).
    auto stage = [&](int tile, int buf) {
#pragma unroll
        for (int i = 0; i < 4; ++i) {
            const int row = i * 16 + w * 4 + lh;
            const int swr = ((row & 7) << 1) | ((row >> 3) & 1);
            const int ucol = (l & 15) ^ swr;           // 16B unit in source
            const float* gsrc = xb + (size_t)row * SPA + tile * 64 + ucol * 4;
            __builtin_amdgcn_global_load_lds(
                (const __attribute__((address_space(1))) void*)gsrc,
                (__attribute__((address_space(3))) void*)&Xt[buf][i * 16 + w * 4][0],
                16, 0, 0);
        }
    };

    f32x4 acc[5];
#pragma unroll
    for (int n = 0; n < 5; ++n) acc[n] = (f32x4){0.f, 0.f, 0.f, 0.f};
    float csum[4] = {0.f, 0.f, 0.f, 0.f};

    stage(0, 0);
    asm volatile("s_waitcnt vmcnt(0)" ::: "memory");
    __syncthreads();

    // read-side swizzle constants: row&7 == lr&7, (row>>3)&1 == lr>>3
    const int swl = ((lr & 7) << 1) | (lr >> 3);
    const int u0  = (h * 4 + gq) * 2;      // global 16B unit (first half of chunk)
    const int s0  = u0 ^ swl;              // LDS slot of global unit u0
    const int s1  = s0 ^ 1;                // LDS slot of global unit u0+1

    for (int tile = 0; tile < 16; ++tile) {
        const int buf = tile & 1;
        if (tile + 1 < 16) stage(tile + 1, buf ^ 1);   // flies under compute

        s16x8 frag[4];
#pragma unroll
        for (int cb = 0; cb < 4; ++cb) {
            const float* rowp = &Xt[buf][cb * 16 + lr][0];
            float4 f0 = *reinterpret_cast<const float4*>(rowp + s0 * 4);
            float4 f1 = *reinterpret_cast<const float4*>(rowp + s1 * 4);
            if (half == 0)
                csum[cb] += (f0.x + f0.y) + (f0.z + f0.w) + (f1.x + f1.y) + (f1.z + f1.w);
            frag[cb] = cvt8(f0, f1);
        }

        if (half == 0) {   // tiles (0,0)(0,1)(0,2)(0,3)(1,1)
            acc[0] = __builtin_amdgcn_mfma_f32_16x16x32_bf16(frag[0], frag[0], acc[0], 0, 0, 0);
            acc[1] = __builtin_amdgcn_mfma_f32_16x16x32_bf16(frag[0], frag[1], acc[1], 0, 0, 0);
            acc[2] = __builtin_amdgcn_mfma_f32_16x16x32_bf16(frag[0], frag[2], acc[2], 0, 0, 0);
            acc[3] = __builtin_amdgcn_mfma_f32_16x16x32_bf16(frag[0], frag[3], acc[3], 0, 0, 0);
            acc[4] = __builtin_amdgcn_mfma_f32_16x16x32_bf16(frag[1], frag[1], acc[4], 0, 0, 0);
        } else {           // tiles (1,2)(1,3)(2,2)(2,3)(3,3)
            acc[0] = __builtin_amdgcn_mfma_f32_16x16x32_bf16(frag[1], frag[2], acc[0], 0, 0, 0);
            acc[1] = __builtin_amdgcn_mfma_f32_16x16x32_bf16(frag[1], frag[3], acc[1], 0, 0, 0);
            acc[2] = __builtin_amdgcn_mfma_f32_16x16x32_bf16(frag[2], frag[2], acc[2], 0, 0, 0);
            acc[3] = __builtin_amdgcn_mfma_f32_16x16x32_bf16(frag[2], frag[3], acc[3], 0, 0, 0);
            acc[4] = __builtin_amdgcn_mfma_f32_16x16x32_bf16(frag[3], frag[3], acc[4], 0, 0, 0);
        }

        asm volatile("s_waitcnt vmcnt(0)" ::: "memory");   // next-tile loads landed
        __syncthreads();                 // all reads of buf done; buf^1 ready
    }

    // ---- epilogue: Xt dead; alias Gl/Ssl onto smem ----
    float* Gl  = smem;                   // 64*67 = 4288 floats
    float* Ssl = smem + 4288;            // [4][64], only w=0,2 slots used

    if (half == 0) {
#pragma unroll
        for (int cb = 0; cb < 4; ++cb) {
            float s = csum[cb];
            s += __shfl_xor(s, 16, 64);
            s += __shfl_xor(s, 32, 64);
            if (gq == 0) Ssl[w * 64 + cb * 16 + lr] = s;
        }
    }

    auto emit = [&](int i, int j, int slot, bool first) {
#pragma unroll
        for (int q = 0; q < 4; ++q) {
            const int d = i * 16 + gq * 4 + q;
            const int e = j * 16 + lr;
            const float val = acc[slot][q];
            if (first) {
                Gl[d * 67 + e] = val;
                if (i != j) Gl[e * 67 + d] = val;
            } else {
                Gl[d * 67 + e] += val;
                if (i != j) Gl[e * 67 + d] += val;
            }
        }
    };

    if (h == 0) {        // waves 0,1: disjoint tile sets -> parallel '='
        if (half == 0) { emit(0,0,0,true); emit(0,1,1,true); emit(0,2,2,true); emit(0,3,3,true); emit(1,1,4,true); }
        else           { emit(1,2,0,true); emit(1,3,1,true); emit(2,2,2,true); emit(2,3,3,true); emit(3,3,4,true); }
    }
    __syncthreads();
    if (h == 1) {        // waves 2,3: '+='
        if (half == 0) { emit(0,0,0,false); emit(0,1,1,false); emit(0,2,2,false); emit(0,3,3,false); emit(1,1,4,false); }
        else           { emit(1,2,0,false); emit(1,3,1,false); emit(2,2,2,false); emit(2,3,3,false); emit(3,3,4,false); }
    }
    __syncthreads();

#pragma unroll
    for (int i = 0; i < 16; ++i) {
        const int idx = i * 256 + t;
        const int d = idx >> 6, e = idx & 63;
        Gpart[(size_t)bid * 4096 + idx] = Gl[d * 67 + e];
    }
    if (t < 64)
        Spart[(size_t)bid * 64 + t] = Ssl[0 * 64 + t] + Ssl[2 * 64 + t];
}

// ---------------------------------------------------------------------------
// Kernel 2 (round-8 proven, verbatim): reduce 128 partials/group.
// ---------------------------------------------------------------------------
__global__ __launch_bounds__(256) void zca_reduce(const float* __restrict__ Gpart,
                                                  const float* __restrict__ Spart,
                                                  float* __restrict__ Gsum,
                                                  float* __restrict__ Ssub) {
    const int g = blockIdx.x >> 4, eb = blockIdx.x & 15;
    const int t = threadIdx.x;
    const float* p = Gpart + (size_t)g * 128 * 4096 + eb * 256 + t;
    float a0 = 0.f, a1 = 0.f, a2 = 0.f, a3 = 0.f;
    for (int q = 0; q < 128; q += 4) {
        a0 += p[(size_t)(q + 0) * 4096];
        a1 += p[(size_t)(q + 1) * 4096];
        a2 += p[(size_t)(q + 2) * 4096];
        a3 += p[(size_t)(q + 3) * 4096];
    }
    Gsum[(size_t)g * 4096 + eb * 256 + t] = (a0 + a1) + (a2 + a3);

    if (t < 64) {
        float s = 0.f;
        for (int q = 0; q < 8; ++q)
            s += Spart[(size_t)(g * 128 + eb * 8 + q) * 64 + t];
        Ssub[(size_t)(g * 16 + eb) * 64 + t] = s;
    }
}

// ---------------------------------------------------------------------------
// Kernel 3 (round-11 proven, verbatim): Newton-Schulz, vectorized mm.
// ---------------------------------------------------------------------------
__global__ __launch_bounds__(256) void zca_newton(const float* __restrict__ Gsum,
                                                  const float* __restrict__ Ssub,
                                                  const float* __restrict__ weight,
                                                  const float* __restrict__ bias,
                                                  short* __restrict__ wmB,
                                                  float* __restrict__ betaOut) {
    const int g = blockIdx.x;
    const int t = threadIdx.x;
    const int v = t >> 4;
    const int u = t & 15;
    const int e0 = 4 * u;

    __shared__ float Pm[64 * 68];
    __shared__ float Sn[64 * 68];
    __shared__ float Ta[64 * 68];
    __shared__ float meanS[64];
    __shared__ float scal[2];

    if (t < 64) {
        float s = 0.f;
        for (int eb = 0; eb < 16; ++eb) s += Ssub[(size_t)(g * 16 + eb) * 64 + t];
        meanS[t] = s * (1.0f / MT);
    }
    __syncthreads();

#pragma unroll
    for (int i = 0; i < 4; ++i) {
        const int d = v + 16 * i;
        float4 gv = *reinterpret_cast<const float4*>(Gsum + (size_t)g * 4096 + d * 64 + e0);
        const float md = meanS[d];
        float vals[4] = {gv.x, gv.y, gv.z, gv.w};
#pragma unroll
        for (int c = 0; c < 4; ++c)
            Sn[d * 68 + e0 + c] = vals[c] * (1.0f / MT) - md * meanS[e0 + c]
                                  + ((d == e0 + c) ? EPSV : 0.f);
    }
    __syncthreads();

    if (t < 64) {
        float tr = Sn[t * 68 + t];
        for (int off = 32; off > 0; off >>= 1) tr += __shfl_down(tr, off, 64);
        if (t == 0) {
            scal[0] = 1.0f / tr;
            scal[1] = sqrtf(1.0f / tr);
        }
    }
    __syncthreads();
    const float rTr = scal[0];

#pragma unroll
    for (int i = 0; i < 4; ++i) {
        const int d = v + 16 * i;
#pragma unroll
        for (int c = 0; c < 4; ++c) {
            Sn[d * 68 + e0 + c] *= rTr;
            Pm[d * 68 + e0 + c] = (d == e0 + c) ? 1.f : 0.f;
        }
    }
    __syncthreads();

    auto mm = [&](const float* A, const float* Bm, float r[4][4]) {
#pragma unroll
        for (int i = 0; i < 4; ++i)
#pragma unroll
            for (int c = 0; c < 4; ++c) r[i][c] = 0.f;
        for (int k = 0; k < 64; ++k) {
            float a[4];
#pragma unroll
            for (int i = 0; i < 4; ++i) a[i] = A[(v + 16 * i) * 68 + k];
            const float4 bv = *reinterpret_cast<const float4*>(Bm + k * 68 + e0);
#pragma unroll
            for (int i = 0; i < 4; ++i) {
                r[i][0] += a[i] * bv.x;
                r[i][1] += a[i] * bv.y;
                r[i][2] += a[i] * bv.z;
                r[i][3] += a[i] * bv.w;
            }
        }
    };
    auto storeTa = [&](const float r[4][4]) {
#pragma unroll
        for (int i = 0; i < 4; ++i) {
            float4 o = {r[i][0], r[i][1], r[i][2], r[i][3]};
            *reinterpret_cast<float4*>(&Ta[(v + 16 * i) * 68 + e0]) = o;
        }
    };

    for (int it = 0; it < 5; ++it) {
        float r[4][4];
        mm(Pm, Sn, r);
        storeTa(r);
        __syncthreads();
        mm(Pm, Ta, r);
        __syncthreads();
        storeTa(r);
        __syncthreads();
        mm(Pm, Ta, r);
        __syncthreads();
#pragma unroll
        for (int i = 0; i < 4; ++i) {
            const int d = v + 16 * i;
#pragma unroll
            for (int c = 0; c < 4; ++c)
                Pm[d * 68 + e0 + c] = 1.5f * Pm[d * 68 + e0 + c] - 0.5f * r[i][c];
        }
        __syncthreads();
    }

    const float srTr = scal[1];
#pragma unroll
    for (int i = 0; i < 4; ++i) {
        const int d = v + 16 * i;
        const float wv = weight[g * NCC + d];
        s16x4 pk;
#pragma unroll
        for (int c = 0; c < 4; ++c)
            pk[c] = (short)f2bf(Pm[d * 68 + e0 + c] * srTr * wv);
        *reinterpret_cast<s16x4*>(wmB + (size_t)g * 4096 + d * 64 + e0) = pk;
    }
    if (t < 64) {
        int d = t;
        float s = 0.f;
        for (int e = 0; e < 64; ++e) s += Pm[d * 68 + e] * meanS[e];
        betaOut[g * NCC + d] = bias[g * NCC + d] - weight[g * NCC + d] * srTr * s;
    }
}

// ---------------------------------------------------------------------------
// Kernel 4: MFMA apply (r10-proven pipeline), grid 1024: bid = b*8 + hm*4 + g;
// block covers 64ch x 512m = 8 tiles of 64m (was 4) — halves the per-CU count
// of cold-start prologue drains (8 -> 4 sequential blocks/CU) while LDS stays
// 49.4KB -> 3 resident blocks/CU. Per-tile schedule unchanged.
// ---------------------------------------------------------------------------
__global__ __launch_bounds__(256) void zca_apply(const float* __restrict__ X,
                                                 const short* __restrict__ wmB,
                                                 const float* __restrict__ beta,
                                                 float* __restrict__ out) {
    const int bid = blockIdx.x;
    const int g  = bid & 3;
    const int hm = (bid >> 2) & 1;
    const int b  = bid >> 3;
    const int t  = threadIdx.x;
    const int w  = t >> 6, l = t & 63;
    const int lr = l & 15, gq = l >> 4;

    __shared__ float Xt[2][64][64];   // [buf][e][m] pitch 64 (lane-linear dest)
    __shared__ float Ot[64][68];      // [d][m] pitch 68

    s16x8 wa[4][2];
#pragma unroll
    for (int i = 0; i < 4; ++i)
#pragma unroll
        for (int kc = 0; kc < 2; ++kc)
            wa[i][kc] = *reinterpret_cast<const s16x8*>(
                wmB + (size_t)g * 4096 + (16 * i + lr) * 64 + kc * 32 + gq * 8);

    const int ch = t >> 4, s4 = t & 15;
    float bst[4];
#pragma unroll
    for (int i = 0; i < 4; ++i) bst[i] = beta[g * NCC + i * 16 + ch];

    const float* xb = X + ((size_t)b * NCH + (size_t)g * NCC) * SPA + hm * 512;
    float* ob = out + ((size_t)b * NCH + (size_t)g * NCC) * SPA + hm * 512;

    const int lh = l >> 4;

    auto stage = [&](int tile, int buf) {
#pragma unroll
        for (int i = 0; i < 4; ++i) {
            const float* gsrc = xb + (size_t)(i * 16 + w * 4 + lh) * SPA
                                + tile * 64 + (l & 15) * 4;
            __builtin_amdgcn_global_load_lds(
                (const __attribute__((address_space(1))) void*)gsrc,
                (__attribute__((address_space(3))) void*)&Xt[buf][i * 16 + w * 4][0],
                16, 0, 0);
        }
    };

    stage(0, 0);
    asm volatile("s_waitcnt vmcnt(0)" ::: "memory");
    __syncthreads();

    for (int tile = 0; tile < 8; ++tile) {
        const int buf = tile & 1;
        if (tile + 1 < 8) stage(tile + 1, buf ^ 1);   // flies under compute

        float v[2][8];
#pragma unroll
        for (int kc = 0; kc < 2; ++kc)
#pragma unroll
            for (int j = 0; j < 8; ++j)
                v[kc][j] = Xt[buf][kc * 32 + gq * 8 + j][w * 16 + lr];

        s16x8 bf0 = pack8(v[0]);
        s16x8 bf1 = pack8(v[1]);

        f32x4 acc[4];
#pragma unroll
        for (int i = 0; i < 4; ++i) acc[i] = (f32x4){0.f, 0.f, 0.f, 0.f};
#pragma unroll
        for (int i = 0; i < 4; ++i) {
            acc[i] = __builtin_amdgcn_mfma_f32_16x16x32_bf16(wa[i][0], bf0, acc[i], 0, 0, 0);
            acc[i] = __builtin_amdgcn_mfma_f32_16x16x32_bf16(wa[i][1], bf1, acc[i], 0, 0, 0);
        }

        __syncthreads();                 // (1) prev tile's Ot stores complete

#pragma unroll
        for (int i = 0; i < 4; ++i)
#pragma unroll
            for (int q = 0; q < 4; ++q)
                Ot[16 * i + 4 * gq + q][w * 16 + lr] = acc[i][q];

        asm volatile("s_waitcnt vmcnt(0)" ::: "memory");   // tile+1 loads landed
        __syncthreads();                 // (2) Ot ready; Xt[buf^1] ready for all

#pragma unroll
        for (int i = 0; i < 4; ++i) {
            float4 o = *reinterpret_cast<const float4*>(&Ot[i * 16 + ch][s4 * 4]);
            o.x += bst[i]; o.y += bst[i]; o.z += bst[i]; o.w += bst[i];
            *reinterpret_cast<float4*>(
                ob + (size_t)(i * 16 + ch) * SPA + tile * 64 + s4 * 4) = o;
        }
    }
}

// ---------------------------------------------------------------------------
extern "C" void kernel_launch(void* const* d_in, const int* in_sizes, int n_in,
                              void* d_out, int out_size, void* d_ws, size_t ws_size,
                              hipStream_t stream) {
    const float* X      = (const float*)d_in[0];
    const float* weight = (const float*)d_in[1];
    const float* bias   = (const float*)d_in[2];
    float* out = (float*)d_out;

    // ws (floats): Gpart[512*4096] | Spart[512*64] | Gsum[4*4096] |
    //              Ssub[4*16*64] | beta[256] | wmB (4*4096 shorts)
    float* ws    = (float*)d_ws;
    float* Gpart = ws;
    float* Spart = Gpart + (size_t)512 * 4096;
    float* Gsum  = Spart + (size_t)512 * 64;
    float* Ssub  = Gsum + (size_t)4 * 4096;
    float* betaW = Ssub + (size_t)4 * 16 * 64;
    short* wmB   = (short*)(betaW + 256);

    zca_stats <<<dim3(512),  dim3(256), 0, stream>>>(X, Gpart, Spart);
    zca_reduce<<<dim3(64),   dim3(256), 0, stream>>>(Gpart, Spart, Gsum, Ssub);
    zca_newton<<<dim3(4),    dim3(256), 0, stream>>>(Gsum, Ssub, weight, bias, wmB, betaW);
    zca_apply <<<dim3(1024), dim3(256), 0, stream>>>(X, wmB, betaW, out);
}

// Round 20
// 114.744 us; speedup vs baseline: 1.0202x; 1.0202x over previous
//
#include <hip/hip_runtime.h>
#include <hip/hip_bf16.h>
#include <cstddef>
#include <cstdint>

typedef __attribute__((ext_vector_type(8))) short s16x8;   // bf16 A/B frag
typedef __attribute__((ext_vector_type(4))) short s16x4;
typedef __attribute__((ext_vector_type(4))) float f32x4;   // MFMA acc

namespace {
constexpr int NB   = 128;
constexpr int NCH  = 256;
constexpr int SPA  = 1024;
constexpr int NCC  = 64;
constexpr int MT   = NB * SPA;     // 131072
constexpr float EPSV = 1e-5f;
}

__device__ inline unsigned short f2bf(float f) {
    union { float f; unsigned u; } v; v.f = f;
    unsigned r = v.u + 0x7fffu + ((v.u >> 16) & 1u);   // RNE
    return (unsigned short)(r >> 16);
}

__device__ inline s16x8 cvt8(float4 a, float4 b) {
    union { __hip_bfloat162 h[4]; s16x8 s; } u;
    u.h[0] = __float22bfloat162_rn(make_float2(a.x, a.y));
    u.h[1] = __float22bfloat162_rn(make_float2(a.z, a.w));
    u.h[2] = __float22bfloat162_rn(make_float2(b.x, b.y));
    u.h[3] = __float22bfloat162_rn(make_float2(b.z, b.w));
    return u.s;
}

__device__ inline s16x8 pack8(const float* v) {
    union { __hip_bfloat162 h[4]; s16x8 s; } u;
    u.h[0] = __float22bfloat162_rn(make_float2(v[0], v[1]));
    u.h[1] = __float22bfloat162_rn(make_float2(v[2], v[3]));
    u.h[2] = __float22bfloat162_rn(make_float2(v[4], v[5]));
    u.h[3] = __float22bfloat162_rn(make_float2(v[6], v[7]));
    return u.s;
}

// ---------------------------------------------------------------------------
// Kernel 1 (round-17 proven + T5 setprio): partial Gram via bf16 MFMA,
// gload_lds staging + 16B-unit XOR swizzle (linear LDS dest, pre-swizzled
// global source, swizzled read -> conflict-free 8-phase ds_read_b128),
// double-buffered Xt. setprio(1) around the MFMA cluster: with 2 independent
// blocks/CU at uncorrelated phases, compute waves pre-empt stage waves.
// Grid 512 (g*128+b), 256 thr = 4 waves.
// ---------------------------------------------------------------------------
__global__ __launch_bounds__(256) void zca_stats(const float* __restrict__ X,
                                                 float* __restrict__ Gpart,
                                                 float* __restrict__ Spart) {
    const int bid = blockIdx.x;
    const int g = bid >> 7, b = bid & 127;
    const int t = threadIdx.x;
    const int w = t >> 6, l = t & 63;
    const int lr = l & 15, gq = l >> 4;
    const int h    = w >> 1;   // m-half of tile (0: cols 0-31, 1: 32-63)
    const int half = w & 1;    // MFMA tile subset (0: first 5, 1: last 5)

    __shared__ float smem[2 * 64 * 64];           // Xt[2][64][64] (32 KB)
    float (*Xt)[64][64] = (float (*)[64][64])smem;

    const float* xb = X + ((size_t)b * NCH + (size_t)g * NCC) * SPA;
    const int lh = l >> 4;

    // stage: LDS dest linear (lane*16B); global source col pre-swizzled so
    // LDS unit u of row r holds global unit u ^ sw(r).
    auto stage = [&](int tile, int buf) {
#pragma unroll
        for (int i = 0; i < 4; ++i) {
            const int row = i * 16 + w * 4 + lh;
            const int swr = ((row & 7) << 1) | ((row >> 3) & 1);
            const int ucol = (l & 15) ^ swr;           // 16B unit in source
            const float* gsrc = xb + (size_t)row * SPA + tile * 64 + ucol * 4;
            __builtin_amdgcn_global_load_lds(
                (const __attribute__((address_space(1))) void*)gsrc,
                (__attribute__((address_space(3))) void*)&Xt[buf][i * 16 + w * 4][0],
                16, 0, 0);
        }
    };

    f32x4 acc[5];
#pragma unroll
    for (int n = 0; n < 5; ++n) acc[n] = (f32x4){0.f, 0.f, 0.f, 0.f};
    float csum[4] = {0.f, 0.f, 0.f, 0.f};

    stage(0, 0);
    asm volatile("s_waitcnt vmcnt(0)" ::: "memory");
    __syncthreads();

    // read-side swizzle constants: row&7 == lr&7, (row>>3)&1 == lr>>3
    const int swl = ((lr & 7) << 1) | (lr >> 3);
    const int u0  = (h * 4 + gq) * 2;      // global 16B unit (first half of chunk)
    const int s0  = u0 ^ swl;              // LDS slot of global unit u0
    const int s1  = s0 ^ 1;                // LDS slot of global unit u0+1

    for (int tile = 0; tile < 16; ++tile) {
        const int buf = tile & 1;
        if (tile + 1 < 16) stage(tile + 1, buf ^ 1);   // flies under compute

        s16x8 frag[4];
#pragma unroll
        for (int cb = 0; cb < 4; ++cb) {
            const float* rowp = &Xt[buf][cb * 16 + lr][0];
            float4 f0 = *reinterpret_cast<const float4*>(rowp + s0 * 4);
            float4 f1 = *reinterpret_cast<const float4*>(rowp + s1 * 4);
            if (half == 0)
                csum[cb] += (f0.x + f0.y) + (f0.z + f0.w) + (f1.x + f1.y) + (f1.z + f1.w);
            frag[cb] = cvt8(f0, f1);
        }

        __builtin_amdgcn_s_setprio(1);
        if (half == 0) {   // tiles (0,0)(0,1)(0,2)(0,3)(1,1)
            acc[0] = __builtin_amdgcn_mfma_f32_16x16x32_bf16(frag[0], frag[0], acc[0], 0, 0, 0);
            acc[1] = __builtin_amdgcn_mfma_f32_16x16x32_bf16(frag[0], frag[1], acc[1], 0, 0, 0);
            acc[2] = __builtin_amdgcn_mfma_f32_16x16x32_bf16(frag[0], frag[2], acc[2], 0, 0, 0);
            acc[3] = __builtin_amdgcn_mfma_f32_16x16x32_bf16(frag[0], frag[3], acc[3], 0, 0, 0);
            acc[4] = __builtin_amdgcn_mfma_f32_16x16x32_bf16(frag[1], frag[1], acc[4], 0, 0, 0);
        } else {           // tiles (1,2)(1,3)(2,2)(2,3)(3,3)
            acc[0] = __builtin_amdgcn_mfma_f32_16x16x32_bf16(frag[1], frag[2], acc[0], 0, 0, 0);
            acc[1] = __builtin_amdgcn_mfma_f32_16x16x32_bf16(frag[1], frag[3], acc[1], 0, 0, 0);
            acc[2] = __builtin_amdgcn_mfma_f32_16x16x32_bf16(frag[2], frag[2], acc[2], 0, 0, 0);
            acc[3] = __builtin_amdgcn_mfma_f32_16x16x32_bf16(frag[2], frag[3], acc[3], 0, 0, 0);
            acc[4] = __builtin_amdgcn_mfma_f32_16x16x32_bf16(frag[3], frag[3], acc[4], 0, 0, 0);
        }
        __builtin_amdgcn_s_setprio(0);

        asm volatile("s_waitcnt vmcnt(0)" ::: "memory");   // next-tile loads landed
        __syncthreads();                 // all reads of buf done; buf^1 ready
    }

    // ---- epilogue: Xt dead; alias Gl/Ssl onto smem ----
    float* Gl  = smem;                   // 64*67 = 4288 floats
    float* Ssl = smem + 4288;            // [4][64], only w=0,2 slots used

    if (half == 0) {
#pragma unroll
        for (int cb = 0; cb < 4; ++cb) {
            float s = csum[cb];
            s += __shfl_xor(s, 16, 64);
            s += __shfl_xor(s, 32, 64);
            if (gq == 0) Ssl[w * 64 + cb * 16 + lr] = s;
        }
    }

    auto emit = [&](int i, int j, int slot, bool first) {
#pragma unroll
        for (int q = 0; q < 4; ++q) {
            const int d = i * 16 + gq * 4 + q;
            const int e = j * 16 + lr;
            const float val = acc[slot][q];
            if (first) {
                Gl[d * 67 + e] = val;
                if (i != j) Gl[e * 67 + d] = val;
            } else {
                Gl[d * 67 + e] += val;
                if (i != j) Gl[e * 67 + d] += val;
            }
        }
    };

    if (h == 0) {        // waves 0,1: disjoint tile sets -> parallel '='
        if (half == 0) { emit(0,0,0,true); emit(0,1,1,true); emit(0,2,2,true); emit(0,3,3,true); emit(1,1,4,true); }
        else           { emit(1,2,0,true); emit(1,3,1,true); emit(2,2,2,true); emit(2,3,3,true); emit(3,3,4,true); }
    }
    __syncthreads();
    if (h == 1) {        // waves 2,3: '+='
        if (half == 0) { emit(0,0,0,false); emit(0,1,1,false); emit(0,2,2,false); emit(0,3,3,false); emit(1,1,4,false); }
        else           { emit(1,2,0,false); emit(1,3,1,false); emit(2,2,2,false); emit(2,3,3,false); emit(3,3,4,false); }
    }
    __syncthreads();

#pragma unroll
    for (int i = 0; i < 16; ++i) {
        const int idx = i * 256 + t;
        const int d = idx >> 6, e = idx & 63;
        Gpart[(size_t)bid * 4096 + idx] = Gl[d * 67 + e];
    }
    if (t < 64)
        Spart[(size_t)bid * 64 + t] = Ssl[0 * 64 + t] + Ssl[2 * 64 + t];
}

// ---------------------------------------------------------------------------
// Kernel 2 (round-8 proven, verbatim): reduce 128 partials/group.
// ---------------------------------------------------------------------------
__global__ __launch_bounds__(256) void zca_reduce(const float* __restrict__ Gpart,
                                                  const float* __restrict__ Spart,
                                                  float* __restrict__ Gsum,
                                                  float* __restrict__ Ssub) {
    const int g = blockIdx.x >> 4, eb = blockIdx.x & 15;
    const int t = threadIdx.x;
    const float* p = Gpart + (size_t)g * 128 * 4096 + eb * 256 + t;
    float a0 = 0.f, a1 = 0.f, a2 = 0.f, a3 = 0.f;
    for (int q = 0; q < 128; q += 4) {
        a0 += p[(size_t)(q + 0) * 4096];
        a1 += p[(size_t)(q + 1) * 4096];
        a2 += p[(size_t)(q + 2) * 4096];
        a3 += p[(size_t)(q + 3) * 4096];
    }
    Gsum[(size_t)g * 4096 + eb * 256 + t] = (a0 + a1) + (a2 + a3);

    if (t < 64) {
        float s = 0.f;
        for (int q = 0; q < 8; ++q)
            s += Spart[(size_t)(g * 128 + eb * 8 + q) * 64 + t];
        Ssub[(size_t)(g * 16 + eb) * 64 + t] = s;
    }
}

// ---------------------------------------------------------------------------
// Kernel 3 (round-11 proven, verbatim): Newton-Schulz, vectorized mm.
// ---------------------------------------------------------------------------
__global__ __launch_bounds__(256) void zca_newton(const float* __restrict__ Gsum,
                                                  const float* __restrict__ Ssub,
                                                  const float* __restrict__ weight,
                                                  const float* __restrict__ bias,
                                                  short* __restrict__ wmB,
                                                  float* __restrict__ betaOut) {
    const int g = blockIdx.x;
    const int t = threadIdx.x;
    const int v = t >> 4;
    const int u = t & 15;
    const int e0 = 4 * u;

    __shared__ float Pm[64 * 68];
    __shared__ float Sn[64 * 68];
    __shared__ float Ta[64 * 68];
    __shared__ float meanS[64];
    __shared__ float scal[2];

    if (t < 64) {
        float s = 0.f;
        for (int eb = 0; eb < 16; ++eb) s += Ssub[(size_t)(g * 16 + eb) * 64 + t];
        meanS[t] = s * (1.0f / MT);
    }
    __syncthreads();

#pragma unroll
    for (int i = 0; i < 4; ++i) {
        const int d = v + 16 * i;
        float4 gv = *reinterpret_cast<const float4*>(Gsum + (size_t)g * 4096 + d * 64 + e0);
        const float md = meanS[d];
        float vals[4] = {gv.x, gv.y, gv.z, gv.w};
#pragma unroll
        for (int c = 0; c < 4; ++c)
            Sn[d * 68 + e0 + c] = vals[c] * (1.0f / MT) - md * meanS[e0 + c]
                                  + ((d == e0 + c) ? EPSV : 0.f);
    }
    __syncthreads();

    if (t < 64) {
        float tr = Sn[t * 68 + t];
        for (int off = 32; off > 0; off >>= 1) tr += __shfl_down(tr, off, 64);
        if (t == 0) {
            scal[0] = 1.0f / tr;
            scal[1] = sqrtf(1.0f / tr);
        }
    }
    __syncthreads();
    const float rTr = scal[0];

#pragma unroll
    for (int i = 0; i < 4; ++i) {
        const int d = v + 16 * i;
#pragma unroll
        for (int c = 0; c < 4; ++c) {
            Sn[d * 68 + e0 + c] *= rTr;
            Pm[d * 68 + e0 + c] = (d == e0 + c) ? 1.f : 0.f;
        }
    }
    __syncthreads();

    auto mm = [&](const float* A, const float* Bm, float r[4][4]) {
#pragma unroll
        for (int i = 0; i < 4; ++i)
#pragma unroll
            for (int c = 0; c < 4; ++c) r[i][c] = 0.f;
        for (int k = 0; k < 64; ++k) {
            float a[4];
#pragma unroll
            for (int i = 0; i < 4; ++i) a[i] = A[(v + 16 * i) * 68 + k];
            const float4 bv = *reinterpret_cast<const float4*>(Bm + k * 68 + e0);
#pragma unroll
            for (int i = 0; i < 4; ++i) {
                r[i][0] += a[i] * bv.x;
                r[i][1] += a[i] * bv.y;
                r[i][2] += a[i] * bv.z;
                r[i][3] += a[i] * bv.w;
            }
        }
    };
    auto storeTa = [&](const float r[4][4]) {
#pragma unroll
        for (int i = 0; i < 4; ++i) {
            float4 o = {r[i][0], r[i][1], r[i][2], r[i][3]};
            *reinterpret_cast<float4*>(&Ta[(v + 16 * i) * 68 + e0]) = o;
        }
    };

    for (int it = 0; it < 5; ++it) {
        float r[4][4];
        mm(Pm, Sn, r);
        storeTa(r);
        __syncthreads();
        mm(Pm, Ta, r);
        __syncthreads();
        storeTa(r);
        __syncthreads();
        mm(Pm, Ta, r);
        __syncthreads();
#pragma unroll
        for (int i = 0; i < 4; ++i) {
            const int d = v + 16 * i;
#pragma unroll
            for (int c = 0; c < 4; ++c)
                Pm[d * 68 + e0 + c] = 1.5f * Pm[d * 68 + e0 + c] - 0.5f * r[i][c];
        }
        __syncthreads();
    }

    const float srTr = scal[1];
#pragma unroll
    for (int i = 0; i < 4; ++i) {
        const int d = v + 16 * i;
        const float wv = weight[g * NCC + d];
        s16x4 pk;
#pragma unroll
        for (int c = 0; c < 4; ++c)
            pk[c] = (short)f2bf(Pm[d * 68 + e0 + c] * srTr * wv);
        *reinterpret_cast<s16x4*>(wmB + (size_t)g * 4096 + d * 64 + e0) = pk;
    }
    if (t < 64) {
        int d = t;
        float s = 0.f;
        for (int e = 0; e < 64; ++e) s += Pm[d * 68 + e] * meanS[e];
        betaOut[g * NCC + d] = bias[g * NCC + d] - weight[g * NCC + d] * srTr * s;
    }
}

// ---------------------------------------------------------------------------
// Kernel 4 (round-10/17 proven, grid 2048 restored; + T5 setprio around the
// MFMA cluster): MFMA apply, gload_lds + Xt dbuf.
// ---------------------------------------------------------------------------
__global__ __launch_bounds__(256) void zca_apply(const float* __restrict__ X,
                                                 const short* __restrict__ wmB,
                                                 const float* __restrict__ beta,
                                                 float* __restrict__ out) {
    const int bid = blockIdx.x;
    const int g  = bid & 3;
    const int qm = (bid >> 2) & 3;
    const int b  = bid >> 4;
    const int t  = threadIdx.x;
    const int w  = t >> 6, l = t & 63;
    const int lr = l & 15, gq = l >> 4;

    __shared__ float Xt[2][64][64];   // [buf][e][m] pitch 64 (lane-linear dest)
    __shared__ float Ot[64][68];      // [d][m] pitch 68

    s16x8 wa[4][2];
#pragma unroll
    for (int i = 0; i < 4; ++i)
#pragma unroll
        for (int kc = 0; kc < 2; ++kc)
            wa[i][kc] = *reinterpret_cast<const s16x8*>(
                wmB + (size_t)g * 4096 + (16 * i + lr) * 64 + kc * 32 + gq * 8);

    const int ch = t >> 4, s4 = t & 15;
    float bst[4];
#pragma unroll
    for (int i = 0; i < 4; ++i) bst[i] = beta[g * NCC + i * 16 + ch];

    const float* xb = X + ((size_t)b * NCH + (size_t)g * NCC) * SPA + qm * 256;
    float* ob = out + ((size_t)b * NCH + (size_t)g * NCC) * SPA + qm * 256;

    const int lh = l >> 4;

    auto stage = [&](int tile, int buf) {
#pragma unroll
        for (int i = 0; i < 4; ++i) {
            const float* gsrc = xb + (size_t)(i * 16 + w * 4 + lh) * SPA
                                + tile * 64 + (l & 15) * 4;
            __builtin_amdgcn_global_load_lds(
                (const __attribute__((address_space(1))) void*)gsrc,
                (__attribute__((address_space(3))) void*)&Xt[buf][i * 16 + w * 4][0],
                16, 0, 0);
        }
    };

    stage(0, 0);
    asm volatile("s_waitcnt vmcnt(0)" ::: "memory");
    __syncthreads();

    for (int tile = 0; tile < 4; ++tile) {
        const int buf = tile & 1;
        if (tile + 1 < 4) stage(tile + 1, buf ^ 1);   // flies under compute

        float v[2][8];
#pragma unroll
        for (int kc = 0; kc < 2; ++kc)
#pragma unroll
            for (int j = 0; j < 8; ++j)
                v[kc][j] = Xt[buf][kc * 32 + gq * 8 + j][w * 16 + lr];

        s16x8 bf0 = pack8(v[0]);
        s16x8 bf1 = pack8(v[1]);

        f32x4 acc[4];
#pragma unroll
        for (int i = 0; i < 4; ++i) acc[i] = (f32x4){0.f, 0.f, 0.f, 0.f};
        __builtin_amdgcn_s_setprio(1);
#pragma unroll
        for (int i = 0; i < 4; ++i) {
            acc[i] = __builtin_amdgcn_mfma_f32_16x16x32_bf16(wa[i][0], bf0, acc[i], 0, 0, 0);
            acc[i] = __builtin_amdgcn_mfma_f32_16x16x32_bf16(wa[i][1], bf1, acc[i], 0, 0, 0);
        }
        __builtin_amdgcn_s_setprio(0);

        __syncthreads();                 // (1) prev tile's Ot stores complete

#pragma unroll
        for (int i = 0; i < 4; ++i)
#pragma unroll
            for (int q = 0; q < 4; ++q)
                Ot[16 * i + 4 * gq + q][w * 16 + lr] = acc[i][q];

        asm volatile("s_waitcnt vmcnt(0)" ::: "memory");   // tile+1 loads landed
        __syncthreads();                 // (2) Ot ready; Xt[buf^1] ready for all

#pragma unroll
        for (int i = 0; i < 4; ++i) {
            float4 o = *reinterpret_cast<const float4*>(&Ot[i * 16 + ch][s4 * 4]);
            o.x += bst[i]; o.y += bst[i]; o.z += bst[i]; o.w += bst[i];
            *reinterpret_cast<float4*>(
                ob + (size_t)(i * 16 + ch) * SPA + tile * 64 + s4 * 4) = o;
        }
    }
}

// ---------------------------------------------------------------------------
extern "C" void kernel_launch(void* const* d_in, const int* in_sizes, int n_in,
                              void* d_out, int out_size, void* d_ws, size_t ws_size,
                              hipStream_t stream) {
    const float* X      = (const float*)d_in[0];
    const float* weight = (const float*)d_in[1];
    const float* bias   = (const float*)d_in[2];
    float* out = (float*)d_out;

    // ws (floats): Gpart[512*4096] | Spart[512*64] | Gsum[4*4096] |
    //              Ssub[4*16*64] | beta[256] | wmB (4*4096 shorts)
    float* ws    = (float*)d_ws;
    float* Gpart = ws;
    float* Spart = Gpart + (size_t)512 * 4096;
    float* Gsum  = Spart + (size_t)512 * 64;
    float* Ssub  = Gsum + (size_t)4 * 4096;
    float* betaW = Ssub + (size_t)4 * 16 * 64;
    short* wmB   = (short*)(betaW + 256);

    zca_stats <<<dim3(512),  dim3(256), 0, stream>>>(X, Gpart, Spart);
    zca_reduce<<<dim3(64),   dim3(256), 0, stream>>>(Gpart, Spart, Gsum, Ssub);
    zca_newton<<<dim3(4),    dim3(256), 0, stream>>>(Gsum, Ssub, weight, bias, wmB, betaW);
    zca_apply <<<dim3(2048), dim3(256), 0, stream>>>(X, wmB, betaW, out);
}

// Round 21
// 113.042 us; speedup vs baseline: 1.0356x; 1.0151x over previous
//
#include <hip/hip_runtime.h>
#include <hip/hip_bf16.h>
#include <cstddef>
#include <cstdint>

typedef __attribute__((ext_vector_type(8))) short s16x8;   // bf16 A/B frag
typedef __attribute__((ext_vector_type(4))) short s16x4;
typedef __attribute__((ext_vector_type(4))) float f32x4;   // MFMA acc

namespace {
constexpr int NB   = 128;
constexpr int NCH  = 256;
constexpr int SPA  = 1024;
constexpr int NCC  = 64;
constexpr int MT   = NB * SPA;     // 131072
constexpr float EPSV = 1e-5f;
}

__device__ inline unsigned short f2bf(float f) {
    union { float f; unsigned u; } v; v.f = f;
    unsigned r = v.u + 0x7fffu + ((v.u >> 16) & 1u);   // RNE
    return (unsigned short)(r >> 16);
}

__device__ inline s16x8 cvt8(float4 a, float4 b) {
    union { __hip_bfloat162 h[4]; s16x8 s; } u;
    u.h[0] = __float22bfloat162_rn(make_float2(a.x, a.y));
    u.h[1] = __float22bfloat162_rn(make_float2(a.z, a.w));
    u.h[2] = __float22bfloat162_rn(make_float2(b.x, b.y));
    u.h[3] = __float22bfloat162_rn(make_float2(b.z, b.w));
    return u.s;
}

__device__ inline s16x8 pack8(const float* v) {
    union { __hip_bfloat162 h[4]; s16x8 s; } u;
    u.h[0] = __float22bfloat162_rn(make_float2(v[0], v[1]));
    u.h[1] = __float22bfloat162_rn(make_float2(v[2], v[3]));
    u.h[2] = __float22bfloat162_rn(make_float2(v[4], v[5]));
    u.h[3] = __float22bfloat162_rn(make_float2(v[6], v[7]));
    return u.s;
}

// ---------------------------------------------------------------------------
// Kernel 1 (round-17 proven, verbatim — best at 113.25 µs): partial Gram via
// bf16 MFMA, gload_lds staging + 16B-unit XOR swizzle (linear LDS dest,
// pre-swizzled global source, swizzled read -> conflict-free 8-phase
// ds_read_b128), double-buffered Xt. Grid 512 (g*128+b), 256 thr = 4 waves.
// ---------------------------------------------------------------------------
__global__ __launch_bounds__(256) void zca_stats(const float* __restrict__ X,
                                                 float* __restrict__ Gpart,
                                                 float* __restrict__ Spart) {
    const int bid = blockIdx.x;
    const int g = bid >> 7, b = bid & 127;
    const int t = threadIdx.x;
    const int w = t >> 6, l = t & 63;
    const int lr = l & 15, gq = l >> 4;
    const int h    = w >> 1;   // m-half of tile (0: cols 0-31, 1: 32-63)
    const int half = w & 1;    // MFMA tile subset (0: first 5, 1: last 5)

    __shared__ float smem[2 * 64 * 64];           // Xt[2][64][64] (32 KB)
    float (*Xt)[64][64] = (float (*)[64][64])smem;

    const float* xb = X + ((size_t)b * NCH + (size_t)g * NCC) * SPA;
    const int lh = l >> 4;

    // stage: LDS dest linear (lane*16B); global source col pre-swizzled so
    // LDS unit u of row r holds global unit u ^ sw(r).
    auto stage = [&](int tile, int buf) {
#pragma unroll
        for (int i = 0; i < 4; ++i) {
            const int row = i * 16 + w * 4 + lh;
            const int swr = ((row & 7) << 1) | ((row >> 3) & 1);
            const int ucol = (l & 15) ^ swr;           // 16B unit in source
            const float* gsrc = xb + (size_t)row * SPA + tile * 64 + ucol * 4;
            __builtin_amdgcn_global_load_lds(
                (const __attribute__((address_space(1))) void*)gsrc,
                (__attribute__((address_space(3))) void*)&Xt[buf][i * 16 + w * 4][0],
                16, 0, 0);
        }
    };

    f32x4 acc[5];
#pragma unroll
    for (int n = 0; n < 5; ++n) acc[n] = (f32x4){0.f, 0.f, 0.f, 0.f};
    float csum[4] = {0.f, 0.f, 0.f, 0.f};

    stage(0, 0);
    asm volatile("s_waitcnt vmcnt(0)" ::: "memory");
    __syncthreads();

    // read-side swizzle constants: row&7 == lr&7, (row>>3)&1 == lr>>3
    const int swl = ((lr & 7) << 1) | (lr >> 3);
    const int u0  = (h * 4 + gq) * 2;      // global 16B unit (first half of chunk)
    const int s0  = u0 ^ swl;              // LDS slot of global unit u0
    const int s1  = s0 ^ 1;                // LDS slot of global unit u0+1

    for (int tile = 0; tile < 16; ++tile) {
        const int buf = tile & 1;
        if (tile + 1 < 16) stage(tile + 1, buf ^ 1);   // flies under compute

        s16x8 frag[4];
#pragma unroll
        for (int cb = 0; cb < 4; ++cb) {
            const float* rowp = &Xt[buf][cb * 16 + lr][0];
            float4 f0 = *reinterpret_cast<const float4*>(rowp + s0 * 4);
            float4 f1 = *reinterpret_cast<const float4*>(rowp + s1 * 4);
            if (half == 0)
                csum[cb] += (f0.x + f0.y) + (f0.z + f0.w) + (f1.x + f1.y) + (f1.z + f1.w);
            frag[cb] = cvt8(f0, f1);
        }

        if (half == 0) {   // tiles (0,0)(0,1)(0,2)(0,3)(1,1)
            acc[0] = __builtin_amdgcn_mfma_f32_16x16x32_bf16(frag[0], frag[0], acc[0], 0, 0, 0);
            acc[1] = __builtin_amdgcn_mfma_f32_16x16x32_bf16(frag[0], frag[1], acc[1], 0, 0, 0);
            acc[2] = __builtin_amdgcn_mfma_f32_16x16x32_bf16(frag[0], frag[2], acc[2], 0, 0, 0);
            acc[3] = __builtin_amdgcn_mfma_f32_16x16x32_bf16(frag[0], frag[3], acc[3], 0, 0, 0);
            acc[4] = __builtin_amdgcn_mfma_f32_16x16x32_bf16(frag[1], frag[1], acc[4], 0, 0, 0);
        } else {           // tiles (1,2)(1,3)(2,2)(2,3)(3,3)
            acc[0] = __builtin_amdgcn_mfma_f32_16x16x32_bf16(frag[1], frag[2], acc[0], 0, 0, 0);
            acc[1] = __builtin_amdgcn_mfma_f32_16x16x32_bf16(frag[1], frag[3], acc[1], 0, 0, 0);
            acc[2] = __builtin_amdgcn_mfma_f32_16x16x32_bf16(frag[2], frag[2], acc[2], 0, 0, 0);
            acc[3] = __builtin_amdgcn_mfma_f32_16x16x32_bf16(frag[2], frag[3], acc[3], 0, 0, 0);
            acc[4] = __builtin_amdgcn_mfma_f32_16x16x32_bf16(frag[3], frag[3], acc[4], 0, 0, 0);
        }

        asm volatile("s_waitcnt vmcnt(0)" ::: "memory");   // next-tile loads landed
        __syncthreads();                 // all reads of buf done; buf^1 ready
    }

    // ---- epilogue: Xt dead; alias Gl/Ssl onto smem ----
    float* Gl  = smem;                   // 64*67 = 4288 floats
    float* Ssl = smem + 4288;            // [4][64], only w=0,2 slots used

    if (half == 0) {
#pragma unroll
        for (int cb = 0; cb < 4; ++cb) {
            float s = csum[cb];
            s += __shfl_xor(s, 16, 64);
            s += __shfl_xor(s, 32, 64);
            if (gq == 0) Ssl[w * 64 + cb * 16 + lr] = s;
        }
    }

    auto emit = [&](int i, int j, int slot, bool first) {
#pragma unroll
        for (int q = 0; q < 4; ++q) {
            const int d = i * 16 + gq * 4 + q;
            const int e = j * 16 + lr;
            const float val = acc[slot][q];
            if (first) {
                Gl[d * 67 + e] = val;
                if (i != j) Gl[e * 67 + d] = val;
            } else {
                Gl[d * 67 + e] += val;
                if (i != j) Gl[e * 67 + d] += val;
            }
        }
    };

    if (h == 0) {        // waves 0,1: disjoint tile sets -> parallel '='
        if (half == 0) { emit(0,0,0,true); emit(0,1,1,true); emit(0,2,2,true); emit(0,3,3,true); emit(1,1,4,true); }
        else           { emit(1,2,0,true); emit(1,3,1,true); emit(2,2,2,true); emit(2,3,3,true); emit(3,3,4,true); }
    }
    __syncthreads();
    if (h == 1) {        // waves 2,3: '+='
        if (half == 0) { emit(0,0,0,false); emit(0,1,1,false); emit(0,2,2,false); emit(0,3,3,false); emit(1,1,4,false); }
        else           { emit(1,2,0,false); emit(1,3,1,false); emit(2,2,2,false); emit(2,3,3,false); emit(3,3,4,false); }
    }
    __syncthreads();

#pragma unroll
    for (int i = 0; i < 16; ++i) {
        const int idx = i * 256 + t;
        const int d = idx >> 6, e = idx & 63;
        Gpart[(size_t)bid * 4096 + idx] = Gl[d * 67 + e];
    }
    if (t < 64)
        Spart[(size_t)bid * 64 + t] = Ssl[0 * 64 + t] + Ssl[2 * 64 + t];
}

// ---------------------------------------------------------------------------
// Kernel 2 (round-8 proven, verbatim): reduce 128 partials/group.
// ---------------------------------------------------------------------------
__global__ __launch_bounds__(256) void zca_reduce(const float* __restrict__ Gpart,
                                                  const float* __restrict__ Spart,
                                                  float* __restrict__ Gsum,
                                                  float* __restrict__ Ssub) {
    const int g = blockIdx.x >> 4, eb = blockIdx.x & 15;
    const int t = threadIdx.x;
    const float* p = Gpart + (size_t)g * 128 * 4096 + eb * 256 + t;
    float a0 = 0.f, a1 = 0.f, a2 = 0.f, a3 = 0.f;
    for (int q = 0; q < 128; q += 4) {
        a0 += p[(size_t)(q + 0) * 4096];
        a1 += p[(size_t)(q + 1) * 4096];
        a2 += p[(size_t)(q + 2) * 4096];
        a3 += p[(size_t)(q + 3) * 4096];
    }
    Gsum[(size_t)g * 4096 + eb * 256 + t] = (a0 + a1) + (a2 + a3);

    if (t < 64) {
        float s = 0.f;
        for (int q = 0; q < 8; ++q)
            s += Spart[(size_t)(g * 128 + eb * 8 + q) * 64 + t];
        Ssub[(size_t)(g * 16 + eb) * 64 + t] = s;
    }
}

// ---------------------------------------------------------------------------
// Kernel 3 (round-11 proven, verbatim): Newton-Schulz, vectorized mm.
// ---------------------------------------------------------------------------
__global__ __launch_bounds__(256) void zca_newton(const float* __restrict__ Gsum,
                                                  const float* __restrict__ Ssub,
                                                  const float* __restrict__ weight,
                                                  const float* __restrict__ bias,
                                                  short* __restrict__ wmB,
                                                  float* __restrict__ betaOut) {
    const int g = blockIdx.x;
    const int t = threadIdx.x;
    const int v = t >> 4;
    const int u = t & 15;
    const int e0 = 4 * u;

    __shared__ float Pm[64 * 68];
    __shared__ float Sn[64 * 68];
    __shared__ float Ta[64 * 68];
    __shared__ float meanS[64];
    __shared__ float scal[2];

    if (t < 64) {
        float s = 0.f;
        for (int eb = 0; eb < 16; ++eb) s += Ssub[(size_t)(g * 16 + eb) * 64 + t];
        meanS[t] = s * (1.0f / MT);
    }
    __syncthreads();

#pragma unroll
    for (int i = 0; i < 4; ++i) {
        const int d = v + 16 * i;
        float4 gv = *reinterpret_cast<const float4*>(Gsum + (size_t)g * 4096 + d * 64 + e0);
        const float md = meanS[d];
        float vals[4] = {gv.x, gv.y, gv.z, gv.w};
#pragma unroll
        for (int c = 0; c < 4; ++c)
            Sn[d * 68 + e0 + c] = vals[c] * (1.0f / MT) - md * meanS[e0 + c]
                                  + ((d == e0 + c) ? EPSV : 0.f);
    }
    __syncthreads();

    if (t < 64) {
        float tr = Sn[t * 68 + t];
        for (int off = 32; off > 0; off >>= 1) tr += __shfl_down(tr, off, 64);
        if (t == 0) {
            scal[0] = 1.0f / tr;
            scal[1] = sqrtf(1.0f / tr);
        }
    }
    __syncthreads();
    const float rTr = scal[0];

#pragma unroll
    for (int i = 0; i < 4; ++i) {
        const int d = v + 16 * i;
#pragma unroll
        for (int c = 0; c < 4; ++c) {
            Sn[d * 68 + e0 + c] *= rTr;
            Pm[d * 68 + e0 + c] = (d == e0 + c) ? 1.f : 0.f;
        }
    }
    __syncthreads();

    auto mm = [&](const float* A, const float* Bm, float r[4][4]) {
#pragma unroll
        for (int i = 0; i < 4; ++i)
#pragma unroll
            for (int c = 0; c < 4; ++c) r[i][c] = 0.f;
        for (int k = 0; k < 64; ++k) {
            float a[4];
#pragma unroll
            for (int i = 0; i < 4; ++i) a[i] = A[(v + 16 * i) * 68 + k];
            const float4 bv = *reinterpret_cast<const float4*>(Bm + k * 68 + e0);
#pragma unroll
            for (int i = 0; i < 4; ++i) {
                r[i][0] += a[i] * bv.x;
                r[i][1] += a[i] * bv.y;
                r[i][2] += a[i] * bv.z;
                r[i][3] += a[i] * bv.w;
            }
        }
    };
    auto storeTa = [&](const float r[4][4]) {
#pragma unroll
        for (int i = 0; i < 4; ++i) {
            float4 o = {r[i][0], r[i][1], r[i][2], r[i][3]};
            *reinterpret_cast<float4*>(&Ta[(v + 16 * i) * 68 + e0]) = o;
        }
    };

    for (int it = 0; it < 5; ++it) {
        float r[4][4];
        mm(Pm, Sn, r);
        storeTa(r);
        __syncthreads();
        mm(Pm, Ta, r);
        __syncthreads();
        storeTa(r);
        __syncthreads();
        mm(Pm, Ta, r);
        __syncthreads();
#pragma unroll
        for (int i = 0; i < 4; ++i) {
            const int d = v + 16 * i;
#pragma unroll
            for (int c = 0; c < 4; ++c)
                Pm[d * 68 + e0 + c] = 1.5f * Pm[d * 68 + e0 + c] - 0.5f * r[i][c];
        }
        __syncthreads();
    }

    const float srTr = scal[1];
#pragma unroll
    for (int i = 0; i < 4; ++i) {
        const int d = v + 16 * i;
        const float wv = weight[g * NCC + d];
        s16x4 pk;
#pragma unroll
        for (int c = 0; c < 4; ++c)
            pk[c] = (short)f2bf(Pm[d * 68 + e0 + c] * srTr * wv);
        *reinterpret_cast<s16x4*>(wmB + (size_t)g * 4096 + d * 64 + e0) = pk;
    }
    if (t < 64) {
        int d = t;
        float s = 0.f;
        for (int e = 0; e < 64; ++e) s += Pm[d * 68 + e] * meanS[e];
        betaOut[g * NCC + d] = bias[g * NCC + d] - weight[g * NCC + d] * srTr * s;
    }
}

// ---------------------------------------------------------------------------
// Kernel 4 (round-10/17 proven, verbatim): MFMA apply, gload_lds + Xt dbuf.
// Grid 2048: bid = b*16 + qm*4 + g.
// ---------------------------------------------------------------------------
__global__ __launch_bounds__(256) void zca_apply(const float* __restrict__ X,
                                                 const short* __restrict__ wmB,
                                                 const float* __restrict__ beta,
                                                 float* __restrict__ out) {
    const int bid = blockIdx.x;
    const int g  = bid & 3;
    const int qm = (bid >> 2) & 3;
    const int b  = bid >> 4;
    const int t  = threadIdx.x;
    const int w  = t >> 6, l = t & 63;
    const int lr = l & 15, gq = l >> 4;

    __shared__ float Xt[2][64][64];   // [buf][e][m] pitch 64 (lane-linear dest)
    __shared__ float Ot[64][68];      // [d][m] pitch 68

    s16x8 wa[4][2];
#pragma unroll
    for (int i = 0; i < 4; ++i)
#pragma unroll
        for (int kc = 0; kc < 2; ++kc)
            wa[i][kc] = *reinterpret_cast<const s16x8*>(
                wmB + (size_t)g * 4096 + (16 * i + lr) * 64 + kc * 32 + gq * 8);

    const int ch = t >> 4, s4 = t & 15;
    float bst[4];
#pragma unroll
    for (int i = 0; i < 4; ++i) bst[i] = beta[g * NCC + i * 16 + ch];

    const float* xb = X + ((size_t)b * NCH + (size_t)g * NCC) * SPA + qm * 256;
    float* ob = out + ((size_t)b * NCH + (size_t)g * NCC) * SPA + qm * 256;

    const int lh = l >> 4;

    auto stage = [&](int tile, int buf) {
#pragma unroll
        for (int i = 0; i < 4; ++i) {
            const float* gsrc = xb + (size_t)(i * 16 + w * 4 + lh) * SPA
                                + tile * 64 + (l & 15) * 4;
            __builtin_amdgcn_global_load_lds(
                (const __attribute__((address_space(1))) void*)gsrc,
                (__attribute__((address_space(3))) void*)&Xt[buf][i * 16 + w * 4][0],
                16, 0, 0);
        }
    };

    stage(0, 0);
    asm volatile("s_waitcnt vmcnt(0)" ::: "memory");
    __syncthreads();

    for (int tile = 0; tile < 4; ++tile) {
        const int buf = tile & 1;
        if (tile + 1 < 4) stage(tile + 1, buf ^ 1);   // flies under compute

        float v[2][8];
#pragma unroll
        for (int kc = 0; kc < 2; ++kc)
#pragma unroll
            for (int j = 0; j < 8; ++j)
                v[kc][j] = Xt[buf][kc * 32 + gq * 8 + j][w * 16 + lr];

        s16x8 bf0 = pack8(v[0]);
        s16x8 bf1 = pack8(v[1]);

        f32x4 acc[4];
#pragma unroll
        for (int i = 0; i < 4; ++i) acc[i] = (f32x4){0.f, 0.f, 0.f, 0.f};
#pragma unroll
        for (int i = 0; i < 4; ++i) {
            acc[i] = __builtin_amdgcn_mfma_f32_16x16x32_bf16(wa[i][0], bf0, acc[i], 0, 0, 0);
            acc[i] = __builtin_amdgcn_mfma_f32_16x16x32_bf16(wa[i][1], bf1, acc[i], 0, 0, 0);
        }

        __syncthreads();                 // (1) prev tile's Ot stores complete

#pragma unroll
        for (int i = 0; i < 4; ++i)
#pragma unroll
            for (int q = 0; q < 4; ++q)
                Ot[16 * i + 4 * gq + q][w * 16 + lr] = acc[i][q];

        asm volatile("s_waitcnt vmcnt(0)" ::: "memory");   // tile+1 loads landed
        __syncthreads();                 // (2) Ot ready; Xt[buf^1] ready for all

#pragma unroll
        for (int i = 0; i < 4; ++i) {
            float4 o = *reinterpret_cast<const float4*>(&Ot[i * 16 + ch][s4 * 4]);
            o.x += bst[i]; o.y += bst[i]; o.z += bst[i]; o.w += bst[i];
            *reinterpret_cast<float4*>(
                ob + (size_t)(i * 16 + ch) * SPA + tile * 64 + s4 * 4) = o;
        }
    }
}

// ---------------------------------------------------------------------------
extern "C" void kernel_launch(void* const* d_in, const int* in_sizes, int n_in,
                              void* d_out, int out_size, void* d_ws, size_t ws_size,
                              hipStream_t stream) {
    const float* X      = (const float*)d_in[0];
    const float* weight = (const float*)d_in[1];
    const float* bias   = (const float*)d_in[2];
    float* out = (float*)d_out;

    // ws (floats): Gpart[512*4096] | Spart[512*64] | Gsum[4*4096] |
    //              Ssub[4*16*64] | beta[256] | wmB (4*4096 shorts)
    float* ws    = (float*)d_ws;
    float* Gpart = ws;
    float* Spart = Gpart + (size_t)512 * 4096;
    float* Gsum  = Spart + (size_t)512 * 64;
    float* Ssub  = Gsum + (size_t)4 * 4096;
    float* betaW = Ssub + (size_t)4 * 16 * 64;
    short* wmB   = (short*)(betaW + 256);

    zca_stats <<<dim3(512),  dim3(256), 0, stream>>>(X, Gpart, Spart);
    zca_reduce<<<dim3(64),   dim3(256), 0, stream>>>(Gpart, Spart, Gsum, Ssub);
    zca_newton<<<dim3(4),    dim3(256), 0, stream>>>(Gsum, Ssub, weight, bias, wmB, betaW);
    zca_apply <<<dim3(2048), dim3(256), 0, stream>>>(X, wmB, betaW, out);
}